// Round 8
// baseline (666.828 us; speedup 1.0000x reference)
//
#include <hip/hip_runtime.h>
#include <hip/hip_bf16.h>

// SDEnet R8: 256x256 GEMM, 32x32x16 MFMA, FRAG-LINEAR LDS (stage via pre-swizzled global
// gather so every ds_read_b128 is base+lane*16+imm -> zero bank conflicts, no addr VALU).
// R7's 2-phase/k-half schedule, counted vmcnt(4)/tile, setprio. Noise read once.

typedef unsigned short u16;
typedef __attribute__((ext_vector_type(8))) short short8;
typedef __attribute__((ext_vector_type(8))) u16 u16x8;
typedef __attribute__((ext_vector_type(4))) u16 u16x4;
typedef __attribute__((ext_vector_type(4))) float f32x4;
typedef __attribute__((ext_vector_type(16))) float f32x16;

#define BROWS 32768
#define DDIM 1024
#define NBLK 5
#define H_STEP 0.1f
#define SQRT_H 0.31622776601683794f

#define FENCE() asm volatile("" ::: "memory")
#define BARRIER() do { FENCE(); __builtin_amdgcn_s_barrier(); FENCE(); } while (0)

__device__ __forceinline__ float bf2f(u16 u) {
    return __uint_as_float(((unsigned)u) << 16);
}
__device__ __forceinline__ u16 f2bf(float f) {
    unsigned u = __float_as_uint(f);
    unsigned r = 0x7fffu + ((u >> 16) & 1u);
    return (u16)((u + r) >> 16);
}
__device__ __forceinline__ float fast_tanh(float s) {
    float e = __expf(2.0f * s);
    return 1.0f - 2.0f * __builtin_amdgcn_rcpf(e + 1.0f);
}

// async global -> LDS, 16B per lane, wave-uniform LDS base + lane*16
#define GLOAD_LDS16(g, l)                                                        \
    __builtin_amdgcn_global_load_lds(                                            \
        (const __attribute__((address_space(1))) unsigned int*)(const void*)(g), \
        (__attribute__((address_space(3))) unsigned int*)(void*)(l), 16, 0, 0)

// ---------------- pad/convert fp32 -> bf16 (optionally zero-padded cols) ----------------
__global__ __launch_bounds__(256) void pad_cvt(const float* __restrict__ src,
                                               u16* __restrict__ dst,
                                               int R, int C, int Cp) {
    int idx = blockIdx.x * 256 + threadIdx.x;
    if (idx >= R * Cp) return;
    int r = idx / Cp;
    int c = idx - r * Cp;
    float v = (c < C) ? src[(size_t)r * C + c] : 0.0f;
    dst[idx] = f2bf(v);
}

// ---------------- zw[i][b] = sum_d noise[i][b][d] * bw[i][d]  (one wave per row) --------
__global__ __launch_bounds__(256) void zw_kernel(const float* __restrict__ noise,
                                                 const float* __restrict__ bw,
                                                 float* __restrict__ zw) {
    int gw = (blockIdx.x * 256 + threadIdx.x) >> 6;
    int lane = threadIdx.x & 63;
    if (gw >= NBLK * BROWS) return;
    int i = gw >> 15;
    const float* zr = noise + (size_t)gw * DDIM;
    const float* wr = bw + i * DDIM;
    float s = 0.0f;
#pragma unroll
    for (int it = 0; it < 4; ++it) {
        int k = it * 256 + lane * 4;
        f32x4 z = *(const f32x4*)(zr + k);
        f32x4 w = *(const f32x4*)(wr + k);
        s += z.x * w.x + z.y * w.y + z.z * w.z + z.w * w.w;
    }
#pragma unroll
    for (int off = 32; off > 0; off >>= 1) s += __shfl_down(s, off, 64);
    if (lane == 0) zw[gw] = s;
}

// ---------------- 256^2 GEMM, 32x32x16 MFMA, frag-linear LDS ----------------------------
// LDS per buf(65536B): A frag (M=0..7, ks=0..3) at (M*4+ks)*1024; B at +32768 same.
// Frag content: element(lane) = input[row0 + M*32 + (lane&31)][t*64 + ks*16 + (lane>>5)*8 ..+8)
// -> LDS reads are base + lane*16 + IMM (conflict-free); staging gathers the swizzled src.
template <int KK, int EPI>
__global__ __launch_bounds__(512, 2) void gemm256(const u16* __restrict__ Ag,
                                                  const u16* __restrict__ Bg,
                                                  const float* __restrict__ bias,
                                                  u16* __restrict__ outW,
                                                  const u16* __restrict__ outR,
                                                  const float* __restrict__ zw,
                                                  const float* __restrict__ bwv) {
    constexpr int NT = KK / 64;
    static_assert(NT >= 2 && (NT & 1) == 0, "NT even, >=2");
    __shared__ __align__(16) u16 smem[65536];  // 128 KiB
    char* lds = (char*)smem;

    const int bid = blockIdx.x;                 // 512 blocks, 512 % 8 == 0
    const int swz = (bid & 7) * 64 + (bid >> 3);
    const int row0 = (swz >> 2) * 256;
    const int col0 = (swz & 3) * 256;

    const int tid = threadIdx.x;
    const int lane = tid & 63;
    const int wid = tid >> 6;
    const int wm = wid >> 2;   // 2 row-waves (128 rows each)
    const int wn = wid & 3;    // 4 col-waves (64 cols each)

    // ---- staging: per-lane swizzled global base (lane = row32 x k-half8) ----
    const int lr = lane & 31;
    const int lk = (lane >> 5) * 8;
    const u16* aBase = Ag + (size_t)(row0 + lr) * KK + lk;
    const u16* bBase = Bg + (size_t)(col0 + lr) * KK + lk;

    // stage call: wave wid stages frag q = j*8+wid of (tile t, k-half kh); 32 frags/kh.
    // q<16: A(M=q>>1, ks=kh*2+(q&1));  q>=16: B likewise.  1 gload (1KB) per wave.
    auto stageQ = [&](int t, int kh, int j) {
        const int q = j * 8 + wid;
        const int isB = q >> 4;
        const int qq = q & 15;
        const int Mn = qq >> 1;
        const int ks = kh * 2 + (qq & 1);
        const u16* g = (isB ? bBase : aBase) + (size_t)Mn * 32 * KK + t * 64 + ks * 16;
        char* dst = lds + ((t & 1) << 16) + (isB << 15) + (Mn * 4 + ks) * 1024;
        GLOAD_LDS16(g, dst);
    };

    // ---- read addr regs: everything else is a compile-time offset ----
    const int l16 = lane * 16;
    const int aA0 = l16 + (wm << 14);            // A frags M=wm*4+mt -> +(mt*4+ks)*1024
    const int aA1 = aA0 + 65536;
    const int bA0 = l16 + 32768 + (wn << 13);    // B frags N=wn*2+nt -> +(nt*4+ks)*1024
    const int bA1 = bA0 + 65536;

    f32x16 acc[4][2];
#pragma unroll
    for (int mt = 0; mt < 4; ++mt)
#pragma unroll
        for (int nt = 0; nt < 2; ++nt)
#pragma unroll
            for (int e = 0; e < 16; ++e) acc[mt][nt][e] = 0.f;

#define RDA(bufc, imm) (*(const short8*)(lds + ((bufc) ? aA1 : aA0) + (imm)))
#define RDB(bufc, imm) (*(const short8*)(lds + ((bufc) ? bA1 : bA0) + (imm)))
// phase (kh, bufc): stages, counted vm-wait, barrier, {12 linear ds_read + 16 MFMA}.
#define PHASE32(kh, bufc, STGS, VMW)                                                  \
    do {                                                                              \
        STGS;                                                                         \
        VMW;                                                                          \
        FENCE(); __builtin_amdgcn_s_barrier(); FENCE();                               \
        __builtin_amdgcn_s_setprio(1);                                                \
        short8 a0k0 = RDA(bufc, (0 * 4 + (kh) * 2 + 0) * 1024);                       \
        short8 a1k0 = RDA(bufc, (1 * 4 + (kh) * 2 + 0) * 1024);                       \
        short8 a2k0 = RDA(bufc, (2 * 4 + (kh) * 2 + 0) * 1024);                       \
        short8 a3k0 = RDA(bufc, (3 * 4 + (kh) * 2 + 0) * 1024);                       \
        short8 b0k0 = RDB(bufc, (0 * 4 + (kh) * 2 + 0) * 1024);                       \
        short8 b1k0 = RDB(bufc, (1 * 4 + (kh) * 2 + 0) * 1024);                       \
        short8 a0k1 = RDA(bufc, (0 * 4 + (kh) * 2 + 1) * 1024);                       \
        short8 a1k1 = RDA(bufc, (1 * 4 + (kh) * 2 + 1) * 1024);                       \
        short8 a2k1 = RDA(bufc, (2 * 4 + (kh) * 2 + 1) * 1024);                       \
        short8 a3k1 = RDA(bufc, (3 * 4 + (kh) * 2 + 1) * 1024);                       \
        short8 b0k1 = RDB(bufc, (0 * 4 + (kh) * 2 + 1) * 1024);                       \
        short8 b1k1 = RDB(bufc, (1 * 4 + (kh) * 2 + 1) * 1024);                       \
        acc[0][0] = __builtin_amdgcn_mfma_f32_32x32x16_bf16(a0k0, b0k0, acc[0][0], 0, 0, 0); \
        acc[0][1] = __builtin_amdgcn_mfma_f32_32x32x16_bf16(a0k0, b1k0, acc[0][1], 0, 0, 0); \
        acc[1][0] = __builtin_amdgcn_mfma_f32_32x32x16_bf16(a1k0, b0k0, acc[1][0], 0, 0, 0); \
        acc[1][1] = __builtin_amdgcn_mfma_f32_32x32x16_bf16(a1k0, b1k0, acc[1][1], 0, 0, 0); \
        acc[2][0] = __builtin_amdgcn_mfma_f32_32x32x16_bf16(a2k0, b0k0, acc[2][0], 0, 0, 0); \
        acc[2][1] = __builtin_amdgcn_mfma_f32_32x32x16_bf16(a2k0, b1k0, acc[2][1], 0, 0, 0); \
        acc[3][0] = __builtin_amdgcn_mfma_f32_32x32x16_bf16(a3k0, b0k0, acc[3][0], 0, 0, 0); \
        acc[3][1] = __builtin_amdgcn_mfma_f32_32x32x16_bf16(a3k0, b1k0, acc[3][1], 0, 0, 0); \
        acc[0][0] = __builtin_amdgcn_mfma_f32_32x32x16_bf16(a0k1, b0k1, acc[0][0], 0, 0, 0); \
        acc[0][1] = __builtin_amdgcn_mfma_f32_32x32x16_bf16(a0k1, b1k1, acc[0][1], 0, 0, 0); \
        acc[1][0] = __builtin_amdgcn_mfma_f32_32x32x16_bf16(a1k1, b0k1, acc[1][0], 0, 0, 0); \
        acc[1][1] = __builtin_amdgcn_mfma_f32_32x32x16_bf16(a1k1, b1k1, acc[1][1], 0, 0, 0); \
        acc[2][0] = __builtin_amdgcn_mfma_f32_32x32x16_bf16(a2k1, b0k1, acc[2][0], 0, 0, 0); \
        acc[2][1] = __builtin_amdgcn_mfma_f32_32x32x16_bf16(a2k1, b1k1, acc[2][1], 0, 0, 0); \
        acc[3][0] = __builtin_amdgcn_mfma_f32_32x32x16_bf16(a3k1, b0k1, acc[3][0], 0, 0, 0); \
        acc[3][1] = __builtin_amdgcn_mfma_f32_32x32x16_bf16(a3k1, b1k1, acc[3][1], 0, 0, 0); \
        __builtin_amdgcn_s_setprio(0);                                                \
        FENCE(); __builtin_amdgcn_s_barrier(); FENCE();                               \
    } while (0)
#define STG4(t, kh) do { stageQ(t, kh, 0); stageQ(t, kh, 1); stageQ(t, kh, 2); stageQ(t, kh, 3); } while (0)
#define VM4 asm volatile("s_waitcnt vmcnt(4)" ::: "memory")
#define VM0 asm volatile("s_waitcnt vmcnt(0)" ::: "memory")
#define NOSTG ((void)0)
#define NOVM ((void)0)

// tile t (buf c): ph0 stages (t+1, kh1); ph1 stages (t+2, kh0) + VM4 -> (t+1,*) landed.
#define TILE32(t, c)                                                                  \
    do {                                                                              \
        PHASE32(0, c, STG4((t) + 1, 1), NOVM);                                        \
        PHASE32(1, c, STG4((t) + 2, 0), VM4);                                         \
    } while (0)

    // ---- prologue: tile0 both k-halves + tile1 kh0 (12 gloads/wave) ----
    STG4(0, 0); STG4(0, 1);
    STG4(1, 0);
    asm volatile("s_waitcnt vmcnt(4)" ::: "memory");  // tile0 fully landed
    BARRIER();

    for (int t2 = 0; t2 < NT / 2 - 1; ++t2) {
        TILE32(2 * t2, 0);
        TILE32(2 * t2 + 1, 1);
    }
    // ---- peeled tile NT-2 (buf 0): stage only (NT-1, kh1), then drain ----
    PHASE32(0, 0, STG4(NT - 1, 1), NOVM);
    PHASE32(1, 0, NOSTG, VM0);
    // ---- peeled tile NT-1 (buf 1): no stages ----
    PHASE32(0, 1, NOSTG, NOVM);
    PHASE32(1, 1, NOSTG, NOVM);

    // ---- epilogue: C/D 32x32 layout col=lane&31, row=(reg&3)+8*(reg>>2)+4*(lane>>5) ----
    float bcol[2], bwc[2];
#pragma unroll
    for (int nt = 0; nt < 2; ++nt) {
        int cg = col0 + wn * 64 + nt * 32 + (lane & 31);
        bcol[nt] = bias[cg];
        if constexpr (EPI == 1) bwc[nt] = bwv[cg];
    }
    (void)bwc;

    char* wbase = lds + wid * 16384;  // wave-private 128x64 bf16 delta tile
    const int cb = lane & 31;
    const int rq = (lane >> 5) * 4;
#pragma unroll
    for (int mt = 0; mt < 4; ++mt) {
#pragma unroll
        for (int nt = 0; nt < 2; ++nt) {
#pragma unroll
            for (int reg = 0; reg < 16; ++reg) {
                int lrow = mt * 32 + (reg & 3) + 8 * (reg >> 2) + rq;
                int lcol = nt * 32 + cb;
                float t = fast_tanh(acc[mt][nt][reg] + bcol[nt]);
                float d = (EPI == 0) ? t : H_STEP * t;
                int chunk = (lcol >> 3) ^ ((lrow >> 2) & 7);
                *(u16*)(wbase + lrow * 128 + (chunk << 4) + (lcol & 7) * 2) = f2bf(d);
            }
        }
    }

    const int gr_base = row0 + wm * 128;
    const int gc_base = col0 + wn * 64;
#pragma unroll
    for (int it = 0; it < 16; ++it) {
        int lrow = it * 8 + (lane >> 3);
        int chunk = lane & 7;
        int schunk = chunk ^ ((lrow >> 2) & 7);
        u16x8 d8 = *(const u16x8*)(wbase + lrow * 128 + (schunk << 4));
        int grow = gr_base + lrow;
        int gcol = gc_base + chunk * 8;
        size_t gidx = (size_t)grow * DDIM + gcol;
        u16x8 o8;
        if constexpr (EPI == 0) {
            o8 = d8;
        } else {
            u16x8 old8 = *(const u16x8*)(outR + gidx);
            float zr = SQRT_H * zw[grow];
            f32x4 bw0 = *(const f32x4*)(bwv + gcol);
            f32x4 bw1 = *(const f32x4*)(bwv + gcol + 4);
#pragma unroll
            for (int e = 0; e < 8; ++e) {
                float bwe = (e < 4) ? bw0[e] : bw1[e - 4];
                float v = bf2f(old8[e]) + bf2f(d8[e]) + zr * bwe;
                o8[e] = f2bf(v);
            }
        }
        *(u16x8*)(outW + gidx) = o8;
    }
#undef RDA
#undef RDB
#undef PHASE32
#undef STG4
#undef VM4
#undef VM0
#undef NOSTG
#undef NOVM
#undef TILE32
}

// ---------------- y[b] = sum_d out[b][d]*Wlast[d] + blast  (one wave per row) -----------
__global__ __launch_bounds__(256) void last_k(const u16* __restrict__ out,
                                              const float* __restrict__ wlast,
                                              const float* __restrict__ blast,
                                              float* __restrict__ y) {
    int gw = (blockIdx.x * 256 + threadIdx.x) >> 6;
    int lane = threadIdx.x & 63;
    if (gw >= BROWS) return;
    const u16* orow = out + (size_t)gw * DDIM;
    float s = 0.0f;
#pragma unroll
    for (int it = 0; it < 4; ++it) {
        int k = it * 256 + lane * 4;
        u16x4 o = *(const u16x4*)(orow + k);
        f32x4 w = *(const f32x4*)(wlast + k);
        s += bf2f(o.x) * w.x + bf2f(o.y) * w.y + bf2f(o.z) * w.z + bf2f(o.w) * w.w;
    }
#pragma unroll
    for (int off = 32; off > 0; off >>= 1) s += __shfl_down(s, off, 64);
    if (lane == 0) y[gw] = s + blast[0];
}

extern "C" void kernel_launch(void* const* d_in, const int* in_sizes, int n_in,
                              void* d_out, int out_size, void* d_ws, size_t ws_size,
                              hipStream_t stream) {
    const float* x     = (const float*)d_in[0];  // [32768,100]
    const float* W0    = (const float*)d_in[1];  // [1024,100]
    const float* b0    = (const float*)d_in[2];  // [1024]
    const float* Ws    = (const float*)d_in[3];  // [5,1024,1024]
    const float* bs    = (const float*)d_in[4];  // [5,1024]
    const float* bw    = (const float*)d_in[5];  // [5,1024]
    const float* Wlast = (const float*)d_in[6];  // [1,1024]
    const float* blast = (const float*)d_in[7];  // [1]
    const float* noise = (const float*)d_in[8];  // [5,32768,1024]
    float* y = (float*)d_out;                    // [32768]
    (void)in_sizes; (void)n_in; (void)out_size; (void)ws_size;

    char* ws = (char*)d_ws;
    size_t off = 0;
    auto alloc = [&](size_t bytes) {
        char* p = ws + off;
        off += (bytes + 255) & ~(size_t)255;
        return p;
    };
    u16* outB0 = (u16*)alloc((size_t)BROWS * DDIM * 2);       // 64 MB
    u16* outB1 = (u16*)alloc((size_t)BROWS * DDIM * 2);       // 64 MB
    u16* xb    = (u16*)alloc((size_t)BROWS * 128 * 2);        // 8 MB
    u16* W0b   = (u16*)alloc((size_t)DDIM * 128 * 2);         // 256 KB
    u16* Wsb   = (u16*)alloc((size_t)NBLK * DDIM * DDIM * 2); // 10 MB
    float* zw  = (float*)alloc((size_t)NBLK * BROWS * 4);     // 640 KB

    // convert inputs to bf16 (x, W0 padded K 100->128)
    pad_cvt<<<(BROWS * 128 + 255) / 256, 256, 0, stream>>>(x, xb, BROWS, 100, 128);
    pad_cvt<<<(DDIM * 128 + 255) / 256, 256, 0, stream>>>(W0, W0b, DDIM, 100, 128);
    pad_cvt<<<(NBLK * DDIM * DDIM + 255) / 256, 256, 0, stream>>>(Ws, Wsb, NBLK * DDIM, DDIM, DDIM);

    // zw[i][b] = noise_i[b] . bw_i   (the ONLY read of noise)
    zw_kernel<<<(NBLK * BROWS) / 4, 256, 0, stream>>>(noise, bw, zw);

    // first layer: out0 = tanh(x @ W0^T + b0)
    gemm256<128, 0><<<512, 512, 0, stream>>>(xb, W0b, b0, outB0,
                                             nullptr, nullptr, nullptr);

    // 5 residual blocks (ping-pong out buffers)
    u16* cur = outB0;
    u16* nxt = outB1;
    for (int i = 0; i < NBLK; ++i) {
        gemm256<1024, 1><<<512, 512, 0, stream>>>(
            cur, Wsb + (size_t)i * DDIM * DDIM, bs + (size_t)i * DDIM, nxt, cur,
            zw + (size_t)i * BROWS, bw + (size_t)i * DDIM);
        u16* t = cur; cur = nxt; nxt = t;
    }

    // y = out @ Wlast^T + blast
    last_k<<<BROWS / 4, 256, 0, stream>>>(cur, Wlast, blast, y);
}